// Round 3
// baseline (412.834 us; speedup 1.0000x reference)
//
#include <hip/hip_runtime.h>
#include <math.h>

#define B_    32
#define T_    512
#define M_    2048
#define L_    1024
#define NMEL_ 80
#define DSPK_ 256

// block-role partition
#define NB_MEL  512            // 32 b x 16 chunks of 128 rows
#define NB_ATTN 1024           // 32 b x 32 chunks of 16 rows
#define NB_DUR  8
#define NB_SPK  32             // one per b
#define NB_TOT  (NB_MEL + NB_ATTN + NB_DUR + NB_SPK)

// ws float offsets; ws[0] is the completion counter (zeroed by a memset node)
#define WS_MEL  16
#define WS_ATTN (WS_MEL + NB_MEL * 2)
#define WS_DUR  (WS_ATTN + NB_ATTN * 2)
#define WS_SPK  (WS_DUR + NB_DUR)

__device__ __forceinline__ void red2(float& a, float& b) {
    __shared__ float la[4], lb[4];
    #pragma unroll
    for (int off = 32; off > 0; off >>= 1) {
        a += __shfl_down(a, off);
        b += __shfl_down(b, off);
    }
    int lane = threadIdx.x & 63, w = threadIdx.x >> 6;
    if (lane == 0) { la[w] = a; lb[w] = b; }
    __syncthreads();
    if (threadIdx.x == 0) {
        a = la[0] + la[1] + la[2] + la[3];
        b = lb[0] + lb[1] + lb[2] + lb[3];
    }
}

__device__ __forceinline__ void red3(float& a, float& b, float& c) {
    __shared__ float la[4], lb[4], lc[4];
    #pragma unroll
    for (int off = 32; off > 0; off >>= 1) {
        a += __shfl_down(a, off);
        b += __shfl_down(b, off);
        c += __shfl_down(c, off);
    }
    int lane = threadIdx.x & 63, w = threadIdx.x >> 6;
    if (lane == 0) { la[w] = a; lb[w] = b; lc[w] = c; }
    __syncthreads();
    if (threadIdx.x == 0) {
        a = la[0] + la[1] + la[2] + la[3];
        b = lb[0] + lb[1] + lb[2] + lb[3];
        c = lc[0] + lc[1] + lc[2] + lc[3];
    }
}

__device__ __forceinline__ float mae4(float4 p, float4 t) {
    return fabsf(p.x - t.x) + fabsf(p.y - t.y) + fabsf(p.z - t.z) + fabsf(p.w - t.w);
}

__device__ __forceinline__ void attn_row(float4 v, int t, float ks, float da,
                                         int l0, float m0, float m1, float m2, float m3,
                                         float& s1, float& s2) {
    float tf = (float)t;
    // match numpy f32: non-fused mul then add/sub, then floor (verified absmax 0)
    float y1f = floorf(__fadd_rn(__fmul_rn(ks, tf), da));
    float y2f = floorf(fmaxf(__fsub_rn(__fmul_rn(ks, tf), da), 0.0f));
    int y1i = (int)y1f, y2i = (int)y2f;
    float w0 = v.x * m0, w1 = v.y * m1, w2 = v.z * m2, w3 = v.w * m3;
    s1 += w0 + w1 + w2 + w3;
    s2 += ((l0 + 0 >= y2i) && (l0 + 0 < y1i)) ? w0 : 0.0f;
    s2 += ((l0 + 1 >= y2i) && (l0 + 1 < y1i)) ? w1 : 0.0f;
    s2 += ((l0 + 2 >= y2i) && (l0 + 2 < y1i)) ? w2 : 0.0f;
    s2 += ((l0 + 3 >= y2i) && (l0 + 3 < y1i)) ? w3 : 0.0f;
}

__global__ __launch_bounds__(256) void fused_kernel(
    const float* __restrict__ mel_t, const float* __restrict__ mel_p,
    const float* __restrict__ post_p, const int* __restrict__ mel_lens,
    const float* __restrict__ attn, const int* __restrict__ xl_,
    const int* __restrict__ ll_, const int* __restrict__ dur_t,
    const float* __restrict__ ldp, const float* __restrict__ spk_p,
    const float* __restrict__ spk_e, float* __restrict__ ws,
    float* __restrict__ out) {
    int blk = blockIdx.x, tid = threadIdx.x;

    if (blk < NB_MEL) {
        // ---- mel MAE partials ----
        int b = blk >> 4, chunk = blk & 15;
        int r0 = chunk << 7;
        int ml = mel_lens[b]; if (ml > M_) ml = M_;
        int rv = ml - r0; if (rv < 0) rv = 0; if (rv > 128) rv = 128;
        int n4 = rv * (NMEL_ / 4);
        const float4* t4 = (const float4*)mel_t + (size_t)(b * M_ + r0) * (NMEL_ / 4);
        const float4* p4 = (const float4*)mel_p + (size_t)(b * M_ + r0) * (NMEL_ / 4);
        const float4* q4 = (const float4*)post_p + (size_t)(b * M_ + r0) * (NMEL_ / 4);
        float s0 = 0.0f, s1 = 0.0f;
        int i = tid;
        for (; i + 256 < n4; i += 512) {
            float4 ta = t4[i],       pa = p4[i],       qa = q4[i];
            float4 tb = t4[i + 256], pb = p4[i + 256], qb = q4[i + 256];
            s0 += mae4(pa, ta) + mae4(pb, tb);
            s1 += mae4(qa, ta) + mae4(qb, tb);
        }
        if (i < n4) {
            float4 ta = t4[i], pa = p4[i], qa = q4[i];
            s0 += mae4(pa, ta);
            s1 += mae4(qa, ta);
        }
        red2(s0, s1);
        if (tid == 0) { ws[WS_MEL + blk * 2] = s0; ws[WS_MEL + blk * 2 + 1] = s1; }

    } else if (blk < NB_MEL + NB_ATTN) {
        // ---- attention S1/S2 partials; skip float4s fully beyond lip_length ----
        int a = blk - NB_MEL;
        int b = a >> 5, chunk = a & 31;
        int t0 = chunk << 4;
        int xl = xl_[b], ll = ll_[b];
        float ks = (float)ll / (float)xl;
        float da = (float)ll * 0.125f;             // DIAR = 8.0
        int tv = ((xl < t0 + 16) ? xl : (t0 + 16)) - t0; if (tv < 0) tv = 0;
        const float4* a4 = (const float4*)attn + ((size_t)b * T_ + t0) * (L_ / 4);
        int l0 = tid * 4;
        bool ldok = (l0 < ll);
        float m0 = (l0 + 0 < ll) ? 1.0f : 0.0f;
        float m1 = (l0 + 1 < ll) ? 1.0f : 0.0f;
        float m2 = (l0 + 2 < ll) ? 1.0f : 0.0f;
        float m3 = (l0 + 3 < ll) ? 1.0f : 0.0f;
        const float4 z4 = make_float4(0.0f, 0.0f, 0.0f, 0.0f);
        float s1 = 0.0f, s2 = 0.0f;
        int r = 0;
        for (; r + 1 < tv; r += 2) {
            float4 va = ldok ? a4[(size_t)r * (L_ / 4) + tid] : z4;
            float4 vb = ldok ? a4[(size_t)(r + 1) * (L_ / 4) + tid] : z4;
            attn_row(va, t0 + r,     ks, da, l0, m0, m1, m2, m3, s1, s2);
            attn_row(vb, t0 + r + 1, ks, da, l0, m0, m1, m2, m3, s1, s2);
        }
        if (r < tv) {
            float4 va = ldok ? a4[(size_t)r * (L_ / 4) + tid] : z4;
            attn_row(va, t0 + r, ks, da, l0, m0, m1, m2, m3, s1, s2);
        }
        red2(s1, s2);
        if (tid == 0) { ws[WS_ATTN + a * 2] = s1; ws[WS_ATTN + a * 2 + 1] = s2; }

    } else if (blk < NB_MEL + NB_ATTN + NB_DUR) {
        // ---- duration MSE partials ----
        int d = blk - (NB_MEL + NB_ATTN);
        int base = d * (B_ * T_ / NB_DUR);
        float s = 0.0f;
        #pragma unroll
        for (int k = 0; k < (B_ * T_ / NB_DUR); k += 256) {
            int i = base + k + tid;
            int b = i >> 9, t = i & (T_ - 1);
            float diff = ldp[i] - logf((float)dur_t[i] + 1.0f);
            s += (t < xl_[b]) ? diff * diff : 0.0f;
        }
        float dummy = 0.0f;
        red2(s, dummy);
        if (tid == 0) ws[WS_DUR + d] = s;

    } else {
        // ---- speaker cosine partials ----
        int b = blk - (NB_MEL + NB_ATTN + NB_DUR);
        float av = spk_p[b * DSPK_ + tid], cv = spk_e[b * DSPK_ + tid];
        float n = av * cv, x = av * av, y = cv * cv;
        red3(n, x, y);
        if (tid == 0) {
            ws[WS_SPK + 3 * b]     = n;
            ws[WS_SPK + 3 * b + 1] = x;
            ws[WS_SPK + 3 * b + 2] = y;
        }
    }

    // ---- last-block-done finalize (counter ws[0] zeroed by memset node) ----
    __shared__ int is_last;
    __threadfence();                         // make partials device-visible
    if (tid == 0) {
        int old = atomicAdd((int*)ws, 1);
        is_last = (old == NB_TOT - 1) ? 1 : 0;
    }
    __syncthreads();
    if (!is_last) return;
    __threadfence();                         // acquire: invalidate L1, see all partials

    __shared__ float sA[256], sB[256];
    __shared__ float perb[B_];
    __shared__ float res[2];

    float s0 = 0.0f, s1 = 0.0f;
    for (int i = tid; i < NB_MEL; i += 256) {
        s0 += ws[WS_MEL + 2 * i];
        s1 += ws[WS_MEL + 2 * i + 1];
    }
    red2(s0, s1);
    if (tid == 0) { res[0] = s0; res[1] = s1; }
    __syncthreads();

    // attn per-b: thread = (b, eighth), each sums 4 chunks
    {
        int b = tid >> 3, c0 = (tid & 7) * 4;
        float t1 = 0.0f, t2 = 0.0f;
        #pragma unroll
        for (int c = c0; c < c0 + 4; ++c) {
            int a = b * 32 + c;
            t1 += ws[WS_ATTN + 2 * a];
            t2 += ws[WS_ATTN + 2 * a + 1];
        }
        sA[tid] = t1; sB[tid] = t2;
    }
    __syncthreads();
    if (tid < B_) {
        float t1 = 0.0f, t2 = 0.0f;
        #pragma unroll
        for (int k = 0; k < 8; ++k) { t1 += sA[tid * 8 + k]; t2 += sB[tid * 8 + k]; }
        perb[tid] = t2 / t1;                 // focus_b
    }
    __syncthreads();
    __shared__ float focus_mean;
    if (tid == 0) {
        float f = 0.0f;
        for (int b = 0; b < B_; ++b) f += perb[b];
        focus_mean = f / (float)B_;
    }
    __syncthreads();

    if (tid < B_) {
        float n = ws[WS_SPK + 3 * tid], x = ws[WS_SPK + 3 * tid + 1], y = ws[WS_SPK + 3 * tid + 2];
        const float eps = 1e-6f;
        float cosv = n / (fmaxf(sqrtf(x), eps) * fmaxf(sqrtf(y), eps));
        perb[tid] = 1.0f - cosv;
        sA[tid] = (float)min(xl_[tid], T_);
        sB[tid] = (float)min(mel_lens[tid], M_);
    }
    __syncthreads();
    if (tid == 0) {
        float spk = 0.0f, sm = 0.0f, cnt = 0.0f;
        for (int b = 0; b < B_; ++b) { spk += perb[b]; sm += sA[b]; cnt += sB[b]; }
        spk /= (float)B_;
        cnt *= (float)NMEL_;

        float sd = 0.0f;
        for (int d = 0; d < NB_DUR; ++d) sd += ws[WS_DUR + d];

        float mel  = res[0] / cnt;
        float post = res[1] / cnt;
        float dur  = sd / sm;
        float dia  = 0.1f * (-logf(focus_mean));
        out[0] = mel + post + dur + spk + dia;
        out[1] = mel;
        out[2] = post;
        out[3] = spk;
        out[4] = dur;
        out[5] = dia;
    }
}

extern "C" void kernel_launch(void* const* d_in, const int* in_sizes, int n_in,
                              void* d_out, int out_size, void* d_ws, size_t ws_size,
                              hipStream_t stream) {
    (void)in_sizes; (void)n_in; (void)out_size; (void)ws_size;
    const float* mel_t   = (const float*)d_in[2];
    const int*   mel_len = (const int*)  d_in[5];
    const int*   dur_t   = (const int*)  d_in[6];
    const float* mel_p   = (const float*)d_in[8];
    const float* post_p  = (const float*)d_in[9];
    const float* ldp     = (const float*)d_in[10];
    const float* spk_p   = (const float*)d_in[14];
    const float* spk_e   = (const float*)d_in[15];
    const float* attn    = (const float*)d_in[16];
    const int*   xl      = (const int*)  d_in[17];
    const int*   ll      = (const int*)  d_in[18];
    float* ws  = (float*)d_ws;
    float* out = (float*)d_out;

    // zero the completion counter (graph-legal: becomes a memset node)
    hipMemsetAsync(d_ws, 0, 4, stream);
    hipLaunchKernelGGL(fused_kernel, dim3(NB_TOT), dim3(256), 0, stream,
                       mel_t, mel_p, post_p, mel_len, attn, xl, ll,
                       dur_t, ldp, spk_p, spk_e, ws, out);
}

// Round 4
// 186.824 us; speedup vs baseline: 2.2097x; 2.2097x over previous
//
#include <hip/hip_runtime.h>
#include <math.h>

#define B_    32
#define T_    512
#define M_    2048
#define L_    1024
#define NMEL_ 80
#define DSPK_ 256

// block-role partition of the fused kernel
#define NB_MEL  512            // 32 b x 16 chunks of 128 rows
#define NB_ATTN 1024           // 32 b x 32 chunks of 16 rows
#define NB_DUR  8
#define NB_SPK  32             // one per b
#define NB_TOT  (NB_MEL + NB_ATTN + NB_DUR + NB_SPK)

// ws layout (floats) — every slot written unconditionally by its owner block.
// NOTE: no cross-block fences/atomics anywhere — kernel-boundary ordering only.
// (R3 lesson: device-scope __threadfence in every block = L2 writeback storm,
//  +240 us on gfx950's non-coherent per-XCD L2s. Two launches are cheaper.)
#define WS_ATTN (NB_MEL * 2)
#define WS_DUR  (WS_ATTN + NB_ATTN * 2)
#define WS_SPK  (WS_DUR + NB_DUR)

__device__ __forceinline__ void red2(float& a, float& b) {
    __shared__ float la[4], lb[4];
    #pragma unroll
    for (int off = 32; off > 0; off >>= 1) {
        a += __shfl_down(a, off);
        b += __shfl_down(b, off);
    }
    int lane = threadIdx.x & 63, w = threadIdx.x >> 6;
    if (lane == 0) { la[w] = a; lb[w] = b; }
    __syncthreads();
    if (threadIdx.x == 0) {
        a = la[0] + la[1] + la[2] + la[3];
        b = lb[0] + lb[1] + lb[2] + lb[3];
    }
}

__device__ __forceinline__ void red3(float& a, float& b, float& c) {
    __shared__ float la[4], lb[4], lc[4];
    #pragma unroll
    for (int off = 32; off > 0; off >>= 1) {
        a += __shfl_down(a, off);
        b += __shfl_down(b, off);
        c += __shfl_down(c, off);
    }
    int lane = threadIdx.x & 63, w = threadIdx.x >> 6;
    if (lane == 0) { la[w] = a; lb[w] = b; lc[w] = c; }
    __syncthreads();
    if (threadIdx.x == 0) {
        a = la[0] + la[1] + la[2] + la[3];
        b = lb[0] + lb[1] + lb[2] + lb[3];
        c = lc[0] + lc[1] + lc[2] + lc[3];
    }
}

__device__ __forceinline__ float mae4(float4 p, float4 t) {
    return fabsf(p.x - t.x) + fabsf(p.y - t.y) + fabsf(p.z - t.z) + fabsf(p.w - t.w);
}

__device__ __forceinline__ void attn_row(float4 v, int t, float ks, float da,
                                         int l0, float m0, float m1, float m2, float m3,
                                         float& s1, float& s2) {
    float tf = (float)t;
    // match numpy f32: non-fused mul then add/sub, then floor (verified absmax 0)
    float y1f = floorf(__fadd_rn(__fmul_rn(ks, tf), da));
    float y2f = floorf(fmaxf(__fsub_rn(__fmul_rn(ks, tf), da), 0.0f));
    int y1i = (int)y1f, y2i = (int)y2f;
    float w0 = v.x * m0, w1 = v.y * m1, w2 = v.z * m2, w3 = v.w * m3;
    s1 += w0 + w1 + w2 + w3;
    s2 += ((l0 + 0 >= y2i) && (l0 + 0 < y1i)) ? w0 : 0.0f;
    s2 += ((l0 + 1 >= y2i) && (l0 + 1 < y1i)) ? w1 : 0.0f;
    s2 += ((l0 + 2 >= y2i) && (l0 + 2 < y1i)) ? w2 : 0.0f;
    s2 += ((l0 + 3 >= y2i) && (l0 + 3 < y1i)) ? w3 : 0.0f;
}

__global__ __launch_bounds__(256) void fused_kernel(
    const float* __restrict__ mel_t, const float* __restrict__ mel_p,
    const float* __restrict__ post_p, const int* __restrict__ mel_lens,
    const float* __restrict__ attn, const int* __restrict__ xl_,
    const int* __restrict__ ll_, const int* __restrict__ dur_t,
    const float* __restrict__ ldp, const float* __restrict__ spk_p,
    const float* __restrict__ spk_e, float* __restrict__ ws) {
    int blk = blockIdx.x, tid = threadIdx.x;

    if (blk < NB_MEL) {
        // ---- mel MAE partials: uniform trip count, unconditional unroll-2 loads ----
        int b = blk >> 4, chunk = blk & 15;
        int r0 = chunk << 7;                       // 128 rows per chunk
        int ml = mel_lens[b]; if (ml > M_) ml = M_;
        int rv = ml - r0; if (rv < 0) rv = 0; if (rv > 128) rv = 128;
        int n4 = rv * (NMEL_ / 4);                 // up to 2560 float4 groups
        const float4* t4 = (const float4*)mel_t + (size_t)(b * M_ + r0) * (NMEL_ / 4);
        const float4* p4 = (const float4*)mel_p + (size_t)(b * M_ + r0) * (NMEL_ / 4);
        const float4* q4 = (const float4*)post_p + (size_t)(b * M_ + r0) * (NMEL_ / 4);
        float s0 = 0.0f, s1 = 0.0f;
        int i = tid;
        for (; i + 256 < n4; i += 512) {
            float4 ta = t4[i],       pa = p4[i],       qa = q4[i];
            float4 tb = t4[i + 256], pb = p4[i + 256], qb = q4[i + 256];
            s0 += mae4(pa, ta) + mae4(pb, tb);
            s1 += mae4(qa, ta) + mae4(qb, tb);
        }
        if (i < n4) {
            float4 ta = t4[i], pa = p4[i], qa = q4[i];
            s0 += mae4(pa, ta);
            s1 += mae4(qa, ta);
        }
        red2(s0, s1);
        if (tid == 0) { ws[blk * 2] = s0; ws[blk * 2 + 1] = s1; }

    } else if (blk < NB_MEL + NB_ATTN) {
        // ---- attention S1/S2 partials; skip float4s fully beyond lip_length ----
        int a = blk - NB_MEL;
        int b = a >> 5, chunk = a & 31;
        int t0 = chunk << 4;                       // 16 rows per chunk
        int xl = xl_[b], ll = ll_[b];
        float ks = (float)ll / (float)xl;
        float da = (float)ll * 0.125f;             // DIAR = 8.0
        int tv = ((xl < t0 + 16) ? xl : (t0 + 16)) - t0; if (tv < 0) tv = 0;
        const float4* a4 = (const float4*)attn + ((size_t)b * T_ + t0) * (L_ / 4);
        int l0 = tid * 4;
        bool ldok = (l0 < ll);                     // whole float4 beyond mask -> skip load
        float m0 = (l0 + 0 < ll) ? 1.0f : 0.0f;
        float m1 = (l0 + 1 < ll) ? 1.0f : 0.0f;
        float m2 = (l0 + 2 < ll) ? 1.0f : 0.0f;
        float m3 = (l0 + 3 < ll) ? 1.0f : 0.0f;
        const float4 z4 = make_float4(0.0f, 0.0f, 0.0f, 0.0f);
        float s1 = 0.0f, s2 = 0.0f;
        int r = 0;
        for (; r + 1 < tv; r += 2) {
            float4 va = ldok ? a4[(size_t)r * (L_ / 4) + tid] : z4;
            float4 vb = ldok ? a4[(size_t)(r + 1) * (L_ / 4) + tid] : z4;
            attn_row(va, t0 + r,     ks, da, l0, m0, m1, m2, m3, s1, s2);
            attn_row(vb, t0 + r + 1, ks, da, l0, m0, m1, m2, m3, s1, s2);
        }
        if (r < tv) {
            float4 va = ldok ? a4[(size_t)r * (L_ / 4) + tid] : z4;
            attn_row(va, t0 + r, ks, da, l0, m0, m1, m2, m3, s1, s2);
        }
        red2(s1, s2);
        if (tid == 0) { ws[WS_ATTN + a * 2] = s1; ws[WS_ATTN + a * 2 + 1] = s2; }

    } else if (blk < NB_MEL + NB_ATTN + NB_DUR) {
        // ---- duration MSE partials ----
        int d = blk - (NB_MEL + NB_ATTN);
        int base = d * (B_ * T_ / NB_DUR);         // 2048 elements per block
        float s = 0.0f;
        #pragma unroll
        for (int k = 0; k < (B_ * T_ / NB_DUR); k += 256) {
            int i = base + k + tid;
            int b = i >> 9, t = i & (T_ - 1);
            float diff = ldp[i] - logf((float)dur_t[i] + 1.0f);
            s += (t < xl_[b]) ? diff * diff : 0.0f;
        }
        float dummy = 0.0f;
        red2(s, dummy);
        if (tid == 0) ws[WS_DUR + d] = s;

    } else {
        // ---- speaker cosine partials: one block per b ----
        int b = blk - (NB_MEL + NB_ATTN + NB_DUR);
        float av = spk_p[b * DSPK_ + tid], cv = spk_e[b * DSPK_ + tid];
        float n = av * cv, x = av * av, y = cv * cv;
        red3(n, x, y);
        if (tid == 0) {
            ws[WS_SPK + 3 * b]     = n;
            ws[WS_SPK + 3 * b + 1] = x;
            ws[WS_SPK + 3 * b + 2] = y;
        }
    }
}

__global__ __launch_bounds__(256) void final_kernel(
    const int* __restrict__ mel_lens, const int* __restrict__ xl_,
    const float* __restrict__ ws, float* __restrict__ out) {
    int tid = threadIdx.x;
    __shared__ float sA[256], sB[256];
    __shared__ float perb[B_];
    __shared__ float res[2];

    // mel partial reduction (512 pairs, 2 per thread)
    float s0 = 0.0f, s1 = 0.0f;
    for (int i = tid; i < NB_MEL; i += 256) { s0 += ws[2 * i]; s1 += ws[2 * i + 1]; }
    red2(s0, s1);
    if (tid == 0) { res[0] = s0; res[1] = s1; }
    __syncthreads();

    // attn per-b sums: thread = (b, eighth), each sums 4 chunks
    {
        int b = tid >> 3, c0 = (tid & 7) * 4;
        float t1 = 0.0f, t2 = 0.0f;
        #pragma unroll
        for (int c = c0; c < c0 + 4; ++c) {
            int a = b * 32 + c;
            t1 += ws[WS_ATTN + 2 * a];
            t2 += ws[WS_ATTN + 2 * a + 1];
        }
        sA[tid] = t1; sB[tid] = t2;
    }
    __syncthreads();
    if (tid < B_) {
        float t1 = 0.0f, t2 = 0.0f;
        #pragma unroll
        for (int k = 0; k < 8; ++k) { t1 += sA[tid * 8 + k]; t2 += sB[tid * 8 + k]; }
        perb[tid] = t2 / t1;                       // focus_b
    }
    __syncthreads();
    __shared__ float focus_mean;
    if (tid == 0) {
        float f = 0.0f;
        for (int b = 0; b < B_; ++b) f += perb[b];
        focus_mean = f / (float)B_;
    }
    __syncthreads();

    // speaker cosine per b + lengths
    if (tid < B_) {
        float n = ws[WS_SPK + 3 * tid], x = ws[WS_SPK + 3 * tid + 1], y = ws[WS_SPK + 3 * tid + 2];
        const float eps = 1e-6f;
        float cosv = n / (fmaxf(sqrtf(x), eps) * fmaxf(sqrtf(y), eps));
        perb[tid] = 1.0f - cosv;
        sA[tid] = (float)min(xl_[tid], T_);
        sB[tid] = (float)min(mel_lens[tid], M_);
    }
    __syncthreads();
    if (tid == 0) {
        float spk = 0.0f, sm = 0.0f, cnt = 0.0f;
        for (int b = 0; b < B_; ++b) { spk += perb[b]; sm += sA[b]; cnt += sB[b]; }
        spk /= (float)B_;
        cnt *= (float)NMEL_;

        float sd = 0.0f;
        for (int d = 0; d < NB_DUR; ++d) sd += ws[WS_DUR + d];

        float mel  = res[0] / cnt;
        float post = res[1] / cnt;
        float dur  = sd / sm;
        float dia  = 0.1f * (-logf(focus_mean));
        out[0] = mel + post + dur + spk + dia;
        out[1] = mel;
        out[2] = post;
        out[3] = spk;
        out[4] = dur;
        out[5] = dia;
    }
}

extern "C" void kernel_launch(void* const* d_in, const int* in_sizes, int n_in,
                              void* d_out, int out_size, void* d_ws, size_t ws_size,
                              hipStream_t stream) {
    (void)in_sizes; (void)n_in; (void)out_size; (void)ws_size;
    const float* mel_t   = (const float*)d_in[2];
    const int*   mel_len = (const int*)  d_in[5];
    const int*   dur_t   = (const int*)  d_in[6];
    const float* mel_p   = (const float*)d_in[8];
    const float* post_p  = (const float*)d_in[9];
    const float* ldp     = (const float*)d_in[10];
    const float* spk_p   = (const float*)d_in[14];
    const float* spk_e   = (const float*)d_in[15];
    const float* attn    = (const float*)d_in[16];
    const int*   xl      = (const int*)  d_in[17];
    const int*   ll      = (const int*)  d_in[18];
    float* ws  = (float*)d_ws;
    float* out = (float*)d_out;

    hipLaunchKernelGGL(fused_kernel, dim3(NB_TOT), dim3(256), 0, stream,
                       mel_t, mel_p, post_p, mel_len, attn, xl, ll,
                       dur_t, ldp, spk_p, spk_e, ws);
    hipLaunchKernelGGL(final_kernel, dim3(1), dim3(256), 0, stream,
                       mel_len, xl, ws, out);
}

// Round 5
// 181.379 us; speedup vs baseline: 2.2761x; 1.0300x over previous
//
#include <hip/hip_runtime.h>
#include <math.h>

#define B_    32
#define T_    512
#define M_    2048
#define L_    1024
#define NMEL_ 80
#define DSPK_ 256

// block-role partition of the fused kernel
#define NB_MEL  1024           // 32 b x 32 chunks of 64 rows (tail smoothing)
#define NB_ATTN 1024           // 32 b x 32 chunks of 16 rows
#define NB_DUR  8
#define NB_SPK  32             // one per b
#define NB_TOT  (NB_MEL + NB_ATTN + NB_DUR + NB_SPK)

// ws layout (floats) — every slot written unconditionally by its owner block.
// NOTE: no cross-block fences/atomics anywhere — kernel-boundary ordering only.
// (R3 lesson: device-scope __threadfence in every block = L2 writeback storm,
//  +240 us on gfx950's non-coherent per-XCD L2s. Two launches are cheaper.)
// (R4 lesson: per-load cndmask skip of masked attn columns cost +5 us vs the
//  unconditional load + mask-multiply — reverted.)
#define WS_ATTN (NB_MEL * 2)
#define WS_DUR  (WS_ATTN + NB_ATTN * 2)
#define WS_SPK  (WS_DUR + NB_DUR)

__device__ __forceinline__ void red2(float& a, float& b) {
    __shared__ float la[4], lb[4];
    #pragma unroll
    for (int off = 32; off > 0; off >>= 1) {
        a += __shfl_down(a, off);
        b += __shfl_down(b, off);
    }
    int lane = threadIdx.x & 63, w = threadIdx.x >> 6;
    if (lane == 0) { la[w] = a; lb[w] = b; }
    __syncthreads();
    if (threadIdx.x == 0) {
        a = la[0] + la[1] + la[2] + la[3];
        b = lb[0] + lb[1] + lb[2] + lb[3];
    }
}

__device__ __forceinline__ void red3(float& a, float& b, float& c) {
    __shared__ float la[4], lb[4], lc[4];
    #pragma unroll
    for (int off = 32; off > 0; off >>= 1) {
        a += __shfl_down(a, off);
        b += __shfl_down(b, off);
        c += __shfl_down(c, off);
    }
    int lane = threadIdx.x & 63, w = threadIdx.x >> 6;
    if (lane == 0) { la[w] = a; lb[w] = b; lc[w] = c; }
    __syncthreads();
    if (threadIdx.x == 0) {
        a = la[0] + la[1] + la[2] + la[3];
        b = lb[0] + lb[1] + lb[2] + lb[3];
        c = lc[0] + lc[1] + lc[2] + lc[3];
    }
}

__device__ __forceinline__ float mae4(float4 p, float4 t) {
    return fabsf(p.x - t.x) + fabsf(p.y - t.y) + fabsf(p.z - t.z) + fabsf(p.w - t.w);
}

__device__ __forceinline__ void attn_row(float4 v, int t, float ks, float da,
                                         int l0, float m0, float m1, float m2, float m3,
                                         float& s1, float& s2) {
    float tf = (float)t;
    // match numpy f32: non-fused mul then add/sub, then floor (verified absmax 0)
    float y1f = floorf(__fadd_rn(__fmul_rn(ks, tf), da));
    float y2f = floorf(fmaxf(__fsub_rn(__fmul_rn(ks, tf), da), 0.0f));
    int y1i = (int)y1f, y2i = (int)y2f;
    float w0 = v.x * m0, w1 = v.y * m1, w2 = v.z * m2, w3 = v.w * m3;
    s1 += w0 + w1 + w2 + w3;
    s2 += ((l0 + 0 >= y2i) && (l0 + 0 < y1i)) ? w0 : 0.0f;
    s2 += ((l0 + 1 >= y2i) && (l0 + 1 < y1i)) ? w1 : 0.0f;
    s2 += ((l0 + 2 >= y2i) && (l0 + 2 < y1i)) ? w2 : 0.0f;
    s2 += ((l0 + 3 >= y2i) && (l0 + 3 < y1i)) ? w3 : 0.0f;
}

__global__ __launch_bounds__(256) void fused_kernel(
    const float* __restrict__ mel_t, const float* __restrict__ mel_p,
    const float* __restrict__ post_p, const int* __restrict__ mel_lens,
    const float* __restrict__ attn, const int* __restrict__ xl_,
    const int* __restrict__ ll_, const int* __restrict__ dur_t,
    const float* __restrict__ ldp, const float* __restrict__ spk_p,
    const float* __restrict__ spk_e, float* __restrict__ ws) {
    int blk = blockIdx.x, tid = threadIdx.x;

    if (blk < NB_MEL) {
        // ---- mel MAE partials: 64-row chunks, unconditional unroll-2 loads ----
        int b = blk >> 5, chunk = blk & 31;
        int r0 = chunk << 6;                       // 64 rows per chunk
        int ml = mel_lens[b]; if (ml > M_) ml = M_;
        int rv = ml - r0; if (rv < 0) rv = 0; if (rv > 64) rv = 64;
        int n4 = rv * (NMEL_ / 4);                 // up to 1280 float4 groups
        const float4* t4 = (const float4*)mel_t + (size_t)(b * M_ + r0) * (NMEL_ / 4);
        const float4* p4 = (const float4*)mel_p + (size_t)(b * M_ + r0) * (NMEL_ / 4);
        const float4* q4 = (const float4*)post_p + (size_t)(b * M_ + r0) * (NMEL_ / 4);
        float s0 = 0.0f, s1 = 0.0f;
        int i = tid;
        for (; i + 256 < n4; i += 512) {
            float4 ta = t4[i],       pa = p4[i],       qa = q4[i];
            float4 tb = t4[i + 256], pb = p4[i + 256], qb = q4[i + 256];
            s0 += mae4(pa, ta) + mae4(pb, tb);
            s1 += mae4(qa, ta) + mae4(qb, tb);
        }
        if (i < n4) {
            float4 ta = t4[i], pa = p4[i], qa = q4[i];
            s0 += mae4(pa, ta);
            s1 += mae4(qa, ta);
        }
        red2(s0, s1);
        if (tid == 0) { ws[blk * 2] = s0; ws[blk * 2 + 1] = s1; }

    } else if (blk < NB_MEL + NB_ATTN) {
        // ---- attention S1/S2 partials: unconditional loads + mask multiply ----
        int a = blk - NB_MEL;
        int b = a >> 5, chunk = a & 31;
        int t0 = chunk << 4;                       // 16 rows per chunk
        int xl = xl_[b], ll = ll_[b];
        float ks = (float)ll / (float)xl;
        float da = (float)ll * 0.125f;             // DIAR = 8.0
        int tv = ((xl < t0 + 16) ? xl : (t0 + 16)) - t0; if (tv < 0) tv = 0;
        const float4* a4 = (const float4*)attn + ((size_t)b * T_ + t0) * (L_ / 4);
        int l0 = tid * 4;
        float m0 = (l0 + 0 < ll) ? 1.0f : 0.0f;
        float m1 = (l0 + 1 < ll) ? 1.0f : 0.0f;
        float m2 = (l0 + 2 < ll) ? 1.0f : 0.0f;
        float m3 = (l0 + 3 < ll) ? 1.0f : 0.0f;
        float s1 = 0.0f, s2 = 0.0f;
        int r = 0;
        for (; r + 1 < tv; r += 2) {
            float4 va = a4[(size_t)r * (L_ / 4) + tid];
            float4 vb = a4[(size_t)(r + 1) * (L_ / 4) + tid];
            attn_row(va, t0 + r,     ks, da, l0, m0, m1, m2, m3, s1, s2);
            attn_row(vb, t0 + r + 1, ks, da, l0, m0, m1, m2, m3, s1, s2);
        }
        if (r < tv) {
            float4 va = a4[(size_t)r * (L_ / 4) + tid];
            attn_row(va, t0 + r, ks, da, l0, m0, m1, m2, m3, s1, s2);
        }
        red2(s1, s2);
        if (tid == 0) { ws[WS_ATTN + a * 2] = s1; ws[WS_ATTN + a * 2 + 1] = s2; }

    } else if (blk < NB_MEL + NB_ATTN + NB_DUR) {
        // ---- duration MSE partials ----
        int d = blk - (NB_MEL + NB_ATTN);
        int base = d * (B_ * T_ / NB_DUR);         // 2048 elements per block
        float s = 0.0f;
        #pragma unroll
        for (int k = 0; k < (B_ * T_ / NB_DUR); k += 256) {
            int i = base + k + tid;
            int b = i >> 9, t = i & (T_ - 1);
            float diff = ldp[i] - logf((float)dur_t[i] + 1.0f);
            s += (t < xl_[b]) ? diff * diff : 0.0f;
        }
        float dummy = 0.0f;
        red2(s, dummy);
        if (tid == 0) ws[WS_DUR + d] = s;

    } else {
        // ---- speaker cosine partials: one block per b ----
        int b = blk - (NB_MEL + NB_ATTN + NB_DUR);
        float av = spk_p[b * DSPK_ + tid], cv = spk_e[b * DSPK_ + tid];
        float n = av * cv, x = av * av, y = cv * cv;
        red3(n, x, y);
        if (tid == 0) {
            ws[WS_SPK + 3 * b]     = n;
            ws[WS_SPK + 3 * b + 1] = x;
            ws[WS_SPK + 3 * b + 2] = y;
        }
    }
}

__global__ __launch_bounds__(256) void final_kernel(
    const int* __restrict__ mel_lens, const int* __restrict__ xl_,
    const float* __restrict__ ws, float* __restrict__ out) {
    int tid = threadIdx.x;
    __shared__ float sA[256], sB[256];
    __shared__ float perb[B_];
    __shared__ float res[2];

    // mel partial reduction (1024 pairs, 4 per thread)
    float s0 = 0.0f, s1 = 0.0f;
    for (int i = tid; i < NB_MEL; i += 256) { s0 += ws[2 * i]; s1 += ws[2 * i + 1]; }
    red2(s0, s1);
    if (tid == 0) { res[0] = s0; res[1] = s1; }
    __syncthreads();

    // attn per-b sums: thread = (b, eighth), each sums 4 chunks
    {
        int b = tid >> 3, c0 = (tid & 7) * 4;
        float t1 = 0.0f, t2 = 0.0f;
        #pragma unroll
        for (int c = c0; c < c0 + 4; ++c) {
            int a = b * 32 + c;
            t1 += ws[WS_ATTN + 2 * a];
            t2 += ws[WS_ATTN + 2 * a + 1];
        }
        sA[tid] = t1; sB[tid] = t2;
    }
    __syncthreads();
    if (tid < B_) {
        float t1 = 0.0f, t2 = 0.0f;
        #pragma unroll
        for (int k = 0; k < 8; ++k) { t1 += sA[tid * 8 + k]; t2 += sB[tid * 8 + k]; }
        perb[tid] = t2 / t1;                       // focus_b
    }
    __syncthreads();
    __shared__ float focus_mean;
    if (tid == 0) {
        float f = 0.0f;
        for (int b = 0; b < B_; ++b) f += perb[b];
        focus_mean = f / (float)B_;
    }
    __syncthreads();

    // speaker cosine per b + lengths
    if (tid < B_) {
        float n = ws[WS_SPK + 3 * tid], x = ws[WS_SPK + 3 * tid + 1], y = ws[WS_SPK + 3 * tid + 2];
        const float eps = 1e-6f;
        float cosv = n / (fmaxf(sqrtf(x), eps) * fmaxf(sqrtf(y), eps));
        perb[tid] = 1.0f - cosv;
        sA[tid] = (float)min(xl_[tid], T_);
        sB[tid] = (float)min(mel_lens[tid], M_);
    }
    __syncthreads();
    if (tid == 0) {
        float spk = 0.0f, sm = 0.0f, cnt = 0.0f;
        for (int b = 0; b < B_; ++b) { spk += perb[b]; sm += sA[b]; cnt += sB[b]; }
        spk /= (float)B_;
        cnt *= (float)NMEL_;

        float sd = 0.0f;
        for (int d = 0; d < NB_DUR; ++d) sd += ws[WS_DUR + d];

        float mel  = res[0] / cnt;
        float post = res[1] / cnt;
        float dur  = sd / sm;
        float dia  = 0.1f * (-logf(focus_mean));
        out[0] = mel + post + dur + spk + dia;
        out[1] = mel;
        out[2] = post;
        out[3] = spk;
        out[4] = dur;
        out[5] = dia;
    }
}

extern "C" void kernel_launch(void* const* d_in, const int* in_sizes, int n_in,
                              void* d_out, int out_size, void* d_ws, size_t ws_size,
                              hipStream_t stream) {
    (void)in_sizes; (void)n_in; (void)out_size; (void)ws_size;
    const float* mel_t   = (const float*)d_in[2];
    const int*   mel_len = (const int*)  d_in[5];
    const int*   dur_t   = (const int*)  d_in[6];
    const float* mel_p   = (const float*)d_in[8];
    const float* post_p  = (const float*)d_in[9];
    const float* ldp     = (const float*)d_in[10];
    const float* spk_p   = (const float*)d_in[14];
    const float* spk_e   = (const float*)d_in[15];
    const float* attn    = (const float*)d_in[16];
    const int*   xl      = (const int*)  d_in[17];
    const int*   ll      = (const int*)  d_in[18];
    float* ws  = (float*)d_ws;
    float* out = (float*)d_out;

    hipLaunchKernelGGL(fused_kernel, dim3(NB_TOT), dim3(256), 0, stream,
                       mel_t, mel_p, post_p, mel_len, attn, xl, ll,
                       dur_t, ldp, spk_p, spk_e, ws);
    hipLaunchKernelGGL(final_kernel, dim3(1), dim3(256), 0, stream,
                       mel_len, xl, ws, out);
}